// Round 1
// baseline (157.687 us; speedup 1.0000x reference)
//
#include <hip/hip_runtime.h>
#include <stdint.h>

// Problem constants (from setup_inputs: B=16,H=768,W=768,N=16,P=640)
#define NIMG 16
#define IMH 768
#define IMW 768
#define NBOX 16
#define PSZ 640
#define IMG_ELEMS (IMH*IMW*3)      // 1769472
#define PATCH_ELEMS (PSZ*PSZ*3)    // 1228800
#define RBLK 64                    // reduction blocks per image
#define PIX_PER_IMG (IMH*IMW)      // 589824
#define BLKS_PER_IMG (PIX_PER_IMG/256)  // 2304

// ---------------- threefry2x32 (JAX key schedule, 20 rounds) ----------------
__device__ __forceinline__ uint32_t rotl32(uint32_t v, int r){ return (v<<r)|(v>>(32-r)); }

__device__ __forceinline__ void threefry(uint32_t k0, uint32_t k1, uint32_t c0, uint32_t c1,
                                         uint32_t& o0, uint32_t& o1){
  uint32_t ks2 = k0 ^ k1 ^ 0x1BD11BDAu;
  uint32_t x0 = c0 + k0, x1 = c1 + k1;
#define TFR(r) { x0 += x1; x1 = rotl32(x1,(r)); x1 ^= x0; }
  TFR(13) TFR(15) TFR(26) TFR(6)
  x0 += k1;  x1 += ks2 + 1u;
  TFR(17) TFR(29) TFR(16) TFR(24)
  x0 += ks2; x1 += k0 + 2u;
  TFR(13) TFR(15) TFR(26) TFR(6)
  x0 += k0;  x1 += k1 + 3u;
  TFR(17) TFR(29) TFR(16) TFR(24)
  x0 += k1;  x1 += ks2 + 4u;
  TFR(13) TFR(15) TFR(26) TFR(6)
  x0 += ks2; x1 += k0 + 5u;
#undef TFR
  o0 = x0; o1 = x1;
}

// partitionable random_bits: element i -> xor of threefry(key, hi=0, lo=i)
__device__ __forceinline__ uint32_t rbits(uint32_t k0, uint32_t k1, uint32_t idx){
  uint32_t a, b; threefry(k0, k1, 0u, idx, a, b); return a ^ b;
}

// JAX uniform [0,1): bitcast((bits>>9)|0x3f800000) - 1
__device__ __forceinline__ float u01(uint32_t bits){
  return __uint_as_float((bits >> 9) | 0x3f800000u) - 1.0f;
}

// JAX uniform(minval,maxval): max(minval, u*(maxval-minval)+minval), unfused
__device__ __forceinline__ float juniform(uint32_t k0, uint32_t k1, uint32_t idx, float mn, float mx){
  float u = u01(rbits(k0, k1, idx));
  float span = __fsub_rn(mx, mn);
  return fmaxf(mn, __fadd_rn(__fmul_rn(u, span), mn));
}

// XLA ErfInv f32 polynomial (value-path only; feeds wmul/badd)
__device__ float erfinv32(float x){
  float w = -log1pf(-x*x);
  float p;
  if (w < 5.0f){
    w = w - 2.5f;
    p = 2.81022636e-08f;
    p = fmaf(p,w, 3.43273939e-07f);
    p = fmaf(p,w,-3.5233877e-06f);
    p = fmaf(p,w,-4.39150654e-06f);
    p = fmaf(p,w, 0.00021858087f);
    p = fmaf(p,w,-0.00125372503f);
    p = fmaf(p,w,-0.00417768164f);
    p = fmaf(p,w, 0.246640727f);
    p = fmaf(p,w, 1.50140941f);
  } else {
    w = sqrtf(w) - 3.0f;
    p = -0.000200214257f;
    p = fmaf(p,w, 0.000100950558f);
    p = fmaf(p,w, 0.00134934322f);
    p = fmaf(p,w,-0.00367342844f);
    p = fmaf(p,w, 0.00573950773f);
    p = fmaf(p,w,-0.0076224613f);
    p = fmaf(p,w, 0.00943887047f);
    p = fmaf(p,w, 1.00167406f);
    p = fmaf(p,w, 2.83297682f);
  }
  return p * x;
}

// ---------------- K0: per-image wmul[3]/badd[3] ----------------
__global__ void k_seed(float* __restrict__ wb){
  int b = threadIdx.x;
  if (b >= NIMG) return;
  uint32_t i0,i1; threefry(0u, 42u, 0u, (uint32_t)b, i0, i1);   // ikeys[b]
  uint32_t kw0,kw1; threefry(i0, i1, 0u, 0u, kw0, kw1);          // kw
  uint32_t kb0,kb1; threefry(i0, i1, 0u, 1u, kb0, kb1);          // kb
  const float lo = -0.99999994f;               // nextafter(-1,0)
  const float span = __fsub_rn(1.0f, lo);      // == 2.0f (tie-to-even)
  const float sq2 = 1.4142135623730951f;
  for (int j = 0; j < 3; j++){
    float uw = u01(rbits(kw0, kw1, (uint32_t)j));
    float rw = fmaxf(lo, __fadd_rn(__fmul_rn(uw, span), lo));
    float nw = __fmul_rn(sq2, erfinv32(rw));
    wb[b*8 + j] = __fadd_rn(0.5f, __fmul_rn(0.1f, nw));          // wmul
    float ub = u01(rbits(kb0, kb1, (uint32_t)j));
    float rb = fmaxf(lo, __fadd_rn(__fmul_rn(ub, span), lo));
    float nb = __fmul_rn(sq2, erfinv32(rb));
    wb[b*8 + 3 + j] = __fmul_rn(0.01f, nb);                      // badd
  }
}

// ---------------- K1: per-image image-sum partials (deterministic) ----------
__global__ __launch_bounds__(256) void k_imgsum(const float* __restrict__ img, double* __restrict__ part){
  int b = blockIdx.x / RBLK;
  int j = blockIdx.x % RBLK;
  const float* base = img + (size_t)b * IMG_ELEMS;
  double s = 0.0;
  for (int i = j*256 + threadIdx.x; i < IMG_ELEMS; i += RBLK*256)
    s += (double)base[i];
  __shared__ double sm[256];
  sm[threadIdx.x] = s; __syncthreads();
  for (int o = 128; o > 0; o >>= 1){
    if (threadIdx.x < o) sm[threadIdx.x] += sm[threadIdx.x + o];
    __syncthreads();
  }
  if (threadIdx.x == 0) part[b*RBLK + j] = sm[0];
}

// ---------------- K2: per-image adjusted-patch-sum partials -----------------
__global__ __launch_bounds__(256) void k_patchsum(const float* __restrict__ patch,
                                                  const float* __restrict__ wb,
                                                  double* __restrict__ part){
  int b = blockIdx.x / RBLK;
  int j = blockIdx.x % RBLK;
  float wm0 = wb[b*8+0], wm1 = wb[b*8+1], wm2 = wb[b*8+2];
  float bd0 = wb[b*8+3], bd1 = wb[b*8+4], bd2 = wb[b*8+5];
  double s = 0.0;
  for (int i = j*256 + threadIdx.x; i < PATCH_ELEMS; i += RBLK*256){
    int c = i % 3;
    float wm = (c==0) ? wm0 : ((c==1) ? wm1 : wm2);
    float bd = (c==0) ? bd0 : ((c==1) ? bd1 : bd2);
    float t = __fadd_rn(__fmul_rn(wm, patch[i]), bd);
    t = fminf(fmaxf(t, -1.0f), 1.0f);
    s += (double)t;
  }
  __shared__ double sm[256];
  sm[threadIdx.x] = s; __syncthreads();
  for (int o = 128; o > 0; o >>= 1){
    if (threadIdx.x < o) sm[threadIdx.x] += sm[threadIdx.x + o];
    __syncthreads();
  }
  if (threadIdx.x == 0) part[b*RBLK + j] = sm[0];
}

// ---------------- K3: finalize means/shift + all 256 box params -------------
// box param layout (16 floats): 0:y0 1:x0 2:d 3:ph 4:top 5:c 6:ca 7:sa
//                               8:sres 9:delta 10:noisek0 11:noisek1 12:valid 13:ph-1
__global__ void k_final(const double* __restrict__ imgpart, const double* __restrict__ patpart,
                        float* __restrict__ shift, float* __restrict__ boxp,
                        const float* __restrict__ boxes, const float* __restrict__ scale){
  int t = threadIdx.x;
  if (t < NIMG){
    double si = 0.0, sp = 0.0;
    for (int j = 0; j < RBLK; j++){ si += imgpart[t*RBLK + j]; sp += patpart[t*RBLK + j]; }
    float mi = (float)(si / (double)IMG_ELEMS);
    float mp = (float)(sp / (double)PATCH_ELEMS);
    shift[t] = __fsub_rn(mi, mp);
  }
  if (t < NIMG*NBOX){
    int b = t / NBOX, i = t % NBOX;
    uint32_t i0,i1;  threefry(0u, 42u, 0u, (uint32_t)b, i0, i1);     // ikeys[b]
    uint32_t kx0,kx1; threefry(i0, i1, 0u, 2u, kx0, kx1);            // kboxes
    uint32_t bk0,bk1; threefry(kx0, kx1, 0u, (uint32_t)i, bk0, bk1); // bkeys[i]
    uint32_t K1a,K1b,K2a,K2b,K3a,K3b,K4a,K4b,K5a,K5b;
    threefry(bk0,bk1,0u,0u,K1a,K1b);  // k1: oy jitter
    threefry(bk0,bk1,0u,1u,K2a,K2b);  // k2: ox jitter
    threefry(bk0,bk1,0u,2u,K3a,K3b);  // k3: angle
    threefry(bk0,bk1,0u,3u,K4a,K4b);  // k4: noise field
    threefry(bk0,bk1,0u,4u,K5a,K5b);  // k5: delta

    const float* bx = boxes + (size_t)t*4;
    float ymin = bx[0], xmin = bx[1], ymax = bx[2], xmax = bx[3];
    float bh = __fsub_rn(ymax, ymin);
    float bw = __fsub_rn(xmax, xmin);
    float longer = fmaxf(bh, bw);
    float sc = scale[0];
    float psize = floorf(__fmul_rn(longer, sc));
    float diag = fminf(__fmul_rn(1.4142135623730951f, psize), 768.0f);

    float mny = __fdiv_rn(__fmul_rn(-0.2f, bh), 2.0f);
    float mxy = __fdiv_rn(__fmul_rn( 0.2f, bh), 2.0f);
    float r1 = juniform(K1a, K1b, 0u, mny, mxy);
    float oy = __fadd_rn(__fadd_rn(ymin, __fdiv_rn(bh, 2.0f)), r1);
    float mnx = __fdiv_rn(__fmul_rn(-0.2f, bw), 2.0f);
    float mxx = __fdiv_rn(__fmul_rn( 0.2f, bw), 2.0f);
    float r2 = juniform(K2a, K2b, 0u, mnx, mxx);
    float ox = __fadd_rn(__fadd_rn(xmin, __fdiv_rn(bw, 2.0f)), r2);

    float hd = __fdiv_rn(diag, 2.0f);
    float y0 = fmaxf(__fsub_rn(oy, hd), 0.0f);
    float x0 = fmaxf(__fsub_rn(ox, hd), 0.0f);
    if (__fadd_rn(y0, diag) > 768.0f) y0 = __fsub_rn(768.0f, diag);
    if (__fadd_rn(x0, diag) > 768.0f) x0 = __fsub_rn(768.0f, diag);
    y0 = floorf(y0);
    x0 = floorf(x0);
    float d  = floorf(diag);
    float ph = psize;
    float top = floorf(__fdiv_rn(__fsub_rn(d, ph), 2.0f));

    const float A20 = 0.3490658503988659f;   // 20 deg in rad, f32
    float ang = juniform(K3a, K3b, 0u, -A20, A20);
    double da = (double)ang;
    float ca = (float)cos(da);               // double-rounded == glibc cosf
    float sa = (float)sin(da);
    float delta = juniform(K5a, K5b, 0u, -0.3f, 0.3f);
    float valid = (__fmul_rn(ph, ph) > 4.0f) ? 1.0f : 0.0f;
    float cc  = __fdiv_rn(__fsub_rn(d, 1.0f), 2.0f);
    float sres = __fdiv_rn(640.0f, ph);      // P / ph

    float* o = boxp + t*16;
    o[0]=y0; o[1]=x0; o[2]=d; o[3]=ph; o[4]=top; o[5]=cc; o[6]=ca; o[7]=sa;
    o[8]=sres; o[9]=delta;
    o[10]=__uint_as_float(K4a); o[11]=__uint_as_float(K4b);
    o[12]=valid; o[13]=__fsub_rn(ph, 1.0f); o[14]=0.0f; o[15]=0.0f;
  }
}

// ---------------- K4: render (last-hit-wins over boxes) ---------------------
__global__ __launch_bounds__(256) void k_render(
    const float* __restrict__ img, const float* __restrict__ patch,
    const float* __restrict__ wb, const float* __restrict__ shift,
    const float* __restrict__ boxp, float* __restrict__ out)
{
  __shared__ float sp[NBOX*16];
  int b = blockIdx.x / BLKS_PER_IMG;
  int blkin = blockIdx.x - b*BLKS_PER_IMG;
  sp[threadIdx.x] = boxp[b*NBOX*16 + threadIdx.x];   // 256 == NBOX*16
  __syncthreads();

  int pix = blkin*256 + threadIdx.x;
  int y = pix / IMW;
  int x = pix - y*IMW;
  float yf = (float)y, xf = (float)x;
  size_t base = (size_t)b*IMG_ELEMS + (size_t)pix*3;
  float r0 = img[base+0], r1 = img[base+1], r2 = img[base+2];

  int win = -1;
  float py = 0.0f, px = 0.0f;
  for (int k = NBOX-1; k >= 0; --k){
    const float* bp = &sp[k*16];
    if (bp[12] == 0.0f) continue;                       // valid
    float u = __fsub_rn(yf, bp[0]);
    if (!(u >= 0.0f && u < bp[2])) continue;            // inside (rows)
    float v = __fsub_rn(xf, bp[1]);
    if (!(v >= 0.0f && v < bp[2])) continue;            // inside (cols)
    float um = __fsub_rn(u, bp[5]);
    float vm = __fsub_rn(v, bp[5]);
    float iu = __fsub_rn(__fadd_rn(bp[5], __fmul_rn(bp[6], um)), __fmul_rn(bp[7], vm));
    float iv = __fadd_rn(__fadd_rn(bp[5], __fmul_rn(bp[7], um)), __fmul_rn(bp[6], vm));
    float pyk = __fsub_rn(iu, bp[4]);
    float pxk = __fsub_rn(iv, bp[4]);
    if (pyk >= 0.0f && pyk <= bp[13] && pxk >= 0.0f && pxk <= bp[13]){
      win = k; py = pyk; px = pxk; break;               // in_patch: last box wins
    }
  }

  if (win >= 0){
    const float* bp = &sp[win*16];
    float sy = __fsub_rn(__fmul_rn(__fadd_rn(py, 0.5f), bp[8]), 0.5f);
    float sx = __fsub_rn(__fmul_rn(__fadd_rn(px, 0.5f), bp[8]), 0.5f);
    float fy = floorf(sy), fx = floorf(sx);
    float wy = __fsub_rn(sy, fy), wx = __fsub_rn(sx, fx);
    int y0i = (int)fminf(fmaxf(fy, 0.0f), 639.0f);
    int y1i = (int)fminf(fmaxf(__fadd_rn(fy, 1.0f), 0.0f), 639.0f);
    int x0i = (int)fminf(fmaxf(fx, 0.0f), 639.0f);
    int x1i = (int)fminf(fmaxf(__fadd_rn(fx, 1.0f), 0.0f), 639.0f);
    float w00 = (1.0f-wy)*(1.0f-wx), w01 = (1.0f-wy)*wx;
    float w10 = wy*(1.0f-wx),        w11 = wy*wx;
    const float* wbb = wb + b*8;
    float shf = shift[b];
    uint32_t n0 = __float_as_uint(bp[10]);
    uint32_t n1 = __float_as_uint(bp[11]);
    float delta = bp[9];
    int i00 = (y0i*PSZ + x0i)*3, i01 = (y0i*PSZ + x1i)*3;
    int i10 = (y1i*PSZ + x0i)*3, i11 = (y1i*PSZ + x1i)*3;
    float ov[3];
    #pragma unroll
    for (int c = 0; c < 3; c++){
      float wm = wbb[c], bd = wbb[3+c];
      float v00 = fminf(fmaxf(__fadd_rn(__fmul_rn(wm, patch[i00+c]), bd), -1.0f), 1.0f);
      v00 = fminf(fmaxf(__fadd_rn(v00, shf), -1.0f), 1.0f);
      float v01 = fminf(fmaxf(__fadd_rn(__fmul_rn(wm, patch[i01+c]), bd), -1.0f), 1.0f);
      v01 = fminf(fmaxf(__fadd_rn(v01, shf), -1.0f), 1.0f);
      float v10 = fminf(fmaxf(__fadd_rn(__fmul_rn(wm, patch[i10+c]), bd), -1.0f), 1.0f);
      v10 = fminf(fmaxf(__fadd_rn(v10, shf), -1.0f), 1.0f);
      float v11 = fminf(fmaxf(__fadd_rn(__fmul_rn(wm, patch[i11+c]), bd), -1.0f), 1.0f);
      v11 = fminf(fmaxf(__fadd_rn(v11, shf), -1.0f), 1.0f);
      float val = v00*w00 + v01*w01 + v10*w10 + v11*w11;
      // noise: uniform(k4,(H,W,3),-0.01,0.01), flat index pix*3+c
      float un = u01(rbits(n0, n1, (uint32_t)(pix*3 + c)));
      float span = __fsub_rn(0.01f, -0.01f);
      float nz = fmaxf(-0.01f, __fadd_rn(__fmul_rn(un, span), -0.01f));
      val = __fadd_rn(__fadd_rn(val, nz), delta);
      ov[c] = fminf(fmaxf(val, -1.0f), 1.0f);
    }
    r0 = ov[0]; r1 = ov[1]; r2 = ov[2];
  }
  out[base+0] = r0; out[base+1] = r1; out[base+2] = r2;
}

// ---------------- host launch ----------------
extern "C" void kernel_launch(void* const* d_in, const int* in_sizes, int n_in,
                              void* d_out, int out_size, void* d_ws, size_t ws_size,
                              hipStream_t stream){
  (void)in_sizes; (void)n_in; (void)out_size; (void)ws_size;
  const float* images = (const float*)d_in[0];
  const float* boxes  = (const float*)d_in[1];
  const float* patch  = (const float*)d_in[2];
  const float* scale  = (const float*)d_in[3];
  float* out = (float*)d_out;

  char* ws = (char*)d_ws;
  double* imgpart = (double*)(ws);              // 16*64*8  = 8192 B
  double* patpart = (double*)(ws + 8192);       // 8192 B
  float*  wb      = (float*)(ws + 16384);       // 16*8*4 = 512 B
  float*  shift   = (float*)(ws + 16896);       // 64 B
  float*  boxp    = (float*)(ws + 17408);       // 256*16*4 = 16384 B (total 33792 B)

  hipLaunchKernelGGL(k_seed,    dim3(1),              dim3(64),  0, stream, wb);
  hipLaunchKernelGGL(k_imgsum,  dim3(NIMG*RBLK),      dim3(256), 0, stream, images, imgpart);
  hipLaunchKernelGGL(k_patchsum,dim3(NIMG*RBLK),      dim3(256), 0, stream, patch, wb, patpart);
  hipLaunchKernelGGL(k_final,   dim3(1),              dim3(256), 0, stream, imgpart, patpart, shift, boxp, boxes, scale);
  hipLaunchKernelGGL(k_render,  dim3(NIMG*BLKS_PER_IMG), dim3(256), 0, stream, images, patch, wb, shift, boxp, out);
}

// Round 2
// 153.832 us; speedup vs baseline: 1.0251x; 1.0251x over previous
//
#include <hip/hip_runtime.h>
#include <stdint.h>

// Problem constants (from setup_inputs: B=16,H=768,W=768,N=16,P=640)
#define NIMG 16
#define IMH 768
#define IMW 768
#define NBOX 16
#define PSZ 640
#define IMG_ELEMS (IMH*IMW*3)      // 1769472
#define PATCH_ELEMS (PSZ*PSZ*3)    // 1228800
#define RBLK 64                    // reduction blocks per image
#define RBOX_BLKS 116              // ceil(172^2 / 256) — max window blocks per box

typedef float f4 __attribute__((ext_vector_type(4)));

// ---------------- threefry2x32 (JAX key schedule, 20 rounds) ----------------
__device__ __forceinline__ uint32_t rotl32(uint32_t v, int r){ return (v<<r)|(v>>(32-r)); }

__device__ __forceinline__ void threefry(uint32_t k0, uint32_t k1, uint32_t c0, uint32_t c1,
                                         uint32_t& o0, uint32_t& o1){
  uint32_t ks2 = k0 ^ k1 ^ 0x1BD11BDAu;
  uint32_t x0 = c0 + k0, x1 = c1 + k1;
#define TFR(r) { x0 += x1; x1 = rotl32(x1,(r)); x1 ^= x0; }
  TFR(13) TFR(15) TFR(26) TFR(6)
  x0 += k1;  x1 += ks2 + 1u;
  TFR(17) TFR(29) TFR(16) TFR(24)
  x0 += ks2; x1 += k0 + 2u;
  TFR(13) TFR(15) TFR(26) TFR(6)
  x0 += k0;  x1 += k1 + 3u;
  TFR(17) TFR(29) TFR(16) TFR(24)
  x0 += k1;  x1 += ks2 + 4u;
  TFR(13) TFR(15) TFR(26) TFR(6)
  x0 += ks2; x1 += k0 + 5u;
#undef TFR
  o0 = x0; o1 = x1;
}

__device__ __forceinline__ uint32_t rbits(uint32_t k0, uint32_t k1, uint32_t idx){
  uint32_t a, b; threefry(k0, k1, 0u, idx, a, b); return a ^ b;
}

__device__ __forceinline__ float u01(uint32_t bits){
  return __uint_as_float((bits >> 9) | 0x3f800000u) - 1.0f;
}

__device__ __forceinline__ float juniform(uint32_t k0, uint32_t k1, uint32_t idx, float mn, float mx){
  float u = u01(rbits(k0, k1, idx));
  float span = __fsub_rn(mx, mn);
  return fmaxf(mn, __fadd_rn(__fmul_rn(u, span), mn));
}

// XLA ErfInv f32 polynomial (value-path only; feeds wmul/badd)
__device__ float erfinv32(float x){
  float w = -log1pf(-x*x);
  float p;
  if (w < 5.0f){
    w = w - 2.5f;
    p = 2.81022636e-08f;
    p = fmaf(p,w, 3.43273939e-07f);
    p = fmaf(p,w,-3.5233877e-06f);
    p = fmaf(p,w,-4.39150654e-06f);
    p = fmaf(p,w, 0.00021858087f);
    p = fmaf(p,w,-0.00125372503f);
    p = fmaf(p,w,-0.00417768164f);
    p = fmaf(p,w, 0.246640727f);
    p = fmaf(p,w, 1.50140941f);
  } else {
    w = sqrtf(w) - 3.0f;
    p = -0.000200214257f;
    p = fmaf(p,w, 0.000100950558f);
    p = fmaf(p,w, 0.00134934322f);
    p = fmaf(p,w,-0.00367342844f);
    p = fmaf(p,w, 0.00573950773f);
    p = fmaf(p,w,-0.0076224613f);
    p = fmaf(p,w, 0.00943887047f);
    p = fmaf(p,w, 1.00167406f);
    p = fmaf(p,w, 2.83297682f);
  }
  return p * x;
}

// ---------------- K0: per-image wmul[3]/badd[3] ----------------
__global__ void k_seed(float* __restrict__ wb){
  int b = threadIdx.x;
  if (b >= NIMG) return;
  uint32_t i0,i1; threefry(0u, 42u, 0u, (uint32_t)b, i0, i1);   // ikeys[b]
  uint32_t kw0,kw1; threefry(i0, i1, 0u, 0u, kw0, kw1);          // kw
  uint32_t kb0,kb1; threefry(i0, i1, 0u, 1u, kb0, kb1);          // kb
  const float lo = -0.99999994f;               // nextafter(-1,0)
  const float span = __fsub_rn(1.0f, lo);
  const float sq2 = 1.4142135623730951f;
  for (int j = 0; j < 3; j++){
    float uw = u01(rbits(kw0, kw1, (uint32_t)j));
    float rw = fmaxf(lo, __fadd_rn(__fmul_rn(uw, span), lo));
    float nw = __fmul_rn(sq2, erfinv32(rw));
    wb[b*8 + j] = __fadd_rn(0.5f, __fmul_rn(0.1f, nw));          // wmul
    float ub = u01(rbits(kb0, kb1, (uint32_t)j));
    float rb = fmaxf(lo, __fadd_rn(__fmul_rn(ub, span), lo));
    float nb = __fmul_rn(sq2, erfinv32(rb));
    wb[b*8 + 3 + j] = __fmul_rn(0.01f, nb);                      // badd
  }
}

// ---------------- K1: copy img->out + per-image sum partials ----------------
__global__ __launch_bounds__(256) void k_copysum(const float* __restrict__ img,
                                                 float* __restrict__ out,
                                                 double* __restrict__ part){
  int b = blockIdx.x >> 6;          // / RBLK
  int j = blockIdx.x & (RBLK-1);
  const f4* src = (const f4*)(img + (size_t)b * IMG_ELEMS);
  f4* dst = (f4*)(out + (size_t)b * IMG_ELEMS);
  const int N4 = IMG_ELEMS/4;       // 442368 ; 442368/(64*256)=27 exact
  double s = 0.0;
  for (int i = j*256 + threadIdx.x; i < N4; i += RBLK*256){
    f4 v = __builtin_nontemporal_load(src + i);
    __builtin_nontemporal_store(v, dst + i);
    s += (double)v.x; s += (double)v.y; s += (double)v.z; s += (double)v.w;
  }
  for (int o = 32; o > 0; o >>= 1) s += __shfl_down(s, o);
  __shared__ double sm[4];
  if ((threadIdx.x & 63) == 0) sm[threadIdx.x >> 6] = s;
  __syncthreads();
  if (threadIdx.x == 0) part[b*RBLK + j] = sm[0]+sm[1]+sm[2]+sm[3];
}

// ---------------- K2: patch read once, 16 adjusted sums ---------------------
__global__ __launch_bounds__(256) void k_patchsum16(const float* __restrict__ patch,
                                                    const float* __restrict__ wb,
                                                    double* __restrict__ part){
  __shared__ float wl[NIMG*8];
  if (threadIdx.x < NIMG*8) wl[threadIdx.x] = wb[threadIdx.x];
  __syncthreads();
  double s[NIMG];
  #pragma unroll
  for (int im = 0; im < NIMG; im++) s[im] = 0.0;
  const f4* p4 = (const f4*)patch;
  const int N4 = PATCH_ELEMS/4;     // 307200
  for (int i = blockIdx.x*256 + threadIdx.x; i < N4; i += 64*256){
    f4 v = __builtin_nontemporal_load(p4 + i);
    int c = (i << 2) % 3;
    #pragma unroll
    for (int q = 0; q < 4; q++){
      float pv = v[q];
      #pragma unroll
      for (int im = 0; im < NIMG; im++){
        float t = __fadd_rn(__fmul_rn(wl[im*8 + c], pv), wl[im*8 + 3 + c]);
        t = fminf(fmaxf(t, -1.0f), 1.0f);
        s[im] += (double)t;
      }
      c = (c == 2) ? 0 : c + 1;
    }
  }
  #pragma unroll
  for (int im = 0; im < NIMG; im++)
    for (int o = 32; o > 0; o >>= 1) s[im] += __shfl_down(s[im], o);
  __shared__ double red[4][NIMG];
  if ((threadIdx.x & 63) == 0){
    int w = threadIdx.x >> 6;
    #pragma unroll
    for (int im = 0; im < NIMG; im++) red[w][im] = s[im];
  }
  __syncthreads();
  if (threadIdx.x < NIMG){
    double t = red[0][threadIdx.x] + red[1][threadIdx.x] + red[2][threadIdx.x] + red[3][threadIdx.x];
    part[threadIdx.x*RBLK + blockIdx.x] = t;
  }
}

// ---------------- K3: finalize means/shift + all 256 box params -------------
// box param layout (16 floats): 0:y0 1:x0 2:d 3:ph 4:top 5:c 6:ca 7:sa
//                               8:sres 9:delta 10:noisek0 11:noisek1 12:valid 13:ph-1
__global__ void k_final(const double* __restrict__ imgpart, const double* __restrict__ patpart,
                        float* __restrict__ shift, float* __restrict__ boxp,
                        const float* __restrict__ boxes, const float* __restrict__ scale){
  int t = threadIdx.x;
  if (t < NIMG){
    double si = 0.0, sp = 0.0;
    for (int j = 0; j < RBLK; j++){ si += imgpart[t*RBLK + j]; sp += patpart[t*RBLK + j]; }
    float mi = (float)(si / (double)IMG_ELEMS);
    float mp = (float)(sp / (double)PATCH_ELEMS);
    shift[t] = __fsub_rn(mi, mp);
  }
  if (t < NIMG*NBOX){
    int b = t / NBOX, i = t % NBOX;
    uint32_t i0,i1;  threefry(0u, 42u, 0u, (uint32_t)b, i0, i1);     // ikeys[b]
    uint32_t kx0,kx1; threefry(i0, i1, 0u, 2u, kx0, kx1);            // kboxes
    uint32_t bk0,bk1; threefry(kx0, kx1, 0u, (uint32_t)i, bk0, bk1); // bkeys[i]
    uint32_t K1a,K1b,K2a,K2b,K3a,K3b,K4a,K4b,K5a,K5b;
    threefry(bk0,bk1,0u,0u,K1a,K1b);  // k1: oy jitter
    threefry(bk0,bk1,0u,1u,K2a,K2b);  // k2: ox jitter
    threefry(bk0,bk1,0u,2u,K3a,K3b);  // k3: angle
    threefry(bk0,bk1,0u,3u,K4a,K4b);  // k4: noise field
    threefry(bk0,bk1,0u,4u,K5a,K5b);  // k5: delta

    const float* bx = boxes + (size_t)t*4;
    float ymin = bx[0], xmin = bx[1], ymax = bx[2], xmax = bx[3];
    float bh = __fsub_rn(ymax, ymin);
    float bw = __fsub_rn(xmax, xmin);
    float longer = fmaxf(bh, bw);
    float sc = scale[0];
    float psize = floorf(__fmul_rn(longer, sc));
    float diag = fminf(__fmul_rn(1.4142135623730951f, psize), 768.0f);

    float mny = __fdiv_rn(__fmul_rn(-0.2f, bh), 2.0f);
    float mxy = __fdiv_rn(__fmul_rn( 0.2f, bh), 2.0f);
    float r1 = juniform(K1a, K1b, 0u, mny, mxy);
    float oy = __fadd_rn(__fadd_rn(ymin, __fdiv_rn(bh, 2.0f)), r1);
    float mnx = __fdiv_rn(__fmul_rn(-0.2f, bw), 2.0f);
    float mxx = __fdiv_rn(__fmul_rn( 0.2f, bw), 2.0f);
    float r2 = juniform(K2a, K2b, 0u, mnx, mxx);
    float ox = __fadd_rn(__fadd_rn(xmin, __fdiv_rn(bw, 2.0f)), r2);

    float hd = __fdiv_rn(diag, 2.0f);
    float y0 = fmaxf(__fsub_rn(oy, hd), 0.0f);
    float x0 = fmaxf(__fsub_rn(ox, hd), 0.0f);
    if (__fadd_rn(y0, diag) > 768.0f) y0 = __fsub_rn(768.0f, diag);
    if (__fadd_rn(x0, diag) > 768.0f) x0 = __fsub_rn(768.0f, diag);
    y0 = floorf(y0);
    x0 = floorf(x0);
    float d  = floorf(diag);
    float ph = psize;
    float top = floorf(__fdiv_rn(__fsub_rn(d, ph), 2.0f));

    const float A20 = 0.3490658503988659f;   // 20 deg in rad, f32
    float ang = juniform(K3a, K3b, 0u, -A20, A20);
    double da = (double)ang;
    float ca = (float)cos(da);
    float sa = (float)sin(da);
    float delta = juniform(K5a, K5b, 0u, -0.3f, 0.3f);
    float valid = (__fmul_rn(ph, ph) > 4.0f) ? 1.0f : 0.0f;
    float cc  = __fdiv_rn(__fsub_rn(d, 1.0f), 2.0f);
    float sres = __fdiv_rn(640.0f, ph);      // P / ph

    float* o = boxp + t*16;
    o[0]=y0; o[1]=x0; o[2]=d; o[3]=ph; o[4]=top; o[5]=cc; o[6]=ca; o[7]=sa;
    o[8]=sres; o[9]=delta;
    o[10]=__uint_as_float(K4a); o[11]=__uint_as_float(K4b);
    o[12]=valid; o[13]=__fsub_rn(ph, 1.0f); o[14]=0.0f; o[15]=0.0f;
  }
}

// ---------------- K4: render covered windows only (winner-writes) -----------
__global__ __launch_bounds__(256) void k_render2(
    const float* __restrict__ patch, const float* __restrict__ wb,
    const float* __restrict__ shift, const float* __restrict__ boxp,
    float* __restrict__ out)
{
  int slot = blockIdx.x / RBOX_BLKS;      // 0..255 : (image, box)
  int t    = blockIdx.x % RBOX_BLKS;
  int b = slot >> 4, k = slot & 15;
  __shared__ float sp[NBOX*16];
  sp[threadIdx.x] = boxp[b*NBOX*16 + threadIdx.x];
  __syncthreads();
  const float* bp = &sp[k*16];
  if (bp[12] == 0.0f) return;             // invalid box (uniform exit)
  int d = (int)bp[2];
  int dd = d*d;

  float y0f = bp[0], x0f = bp[1];
  int y0i = (int)y0f, x0i = (int)x0f;
  float cc = bp[5], ca = bp[6], sa = bp[7], top = bp[4];
  float ph1 = bp[13], sres = bp[8], delta = bp[9];
  uint32_t n0 = __float_as_uint(bp[10]);
  uint32_t n1 = __float_as_uint(bp[11]);
  const float* wbb = wb + b*8;
  float shf = shift[b];

  for (int idx = t*256 + threadIdx.x; idx < dd; idx += RBOX_BLKS*256){
    int row = idx / d;
    int col = idx - row*d;
    int y = y0i + row, x = x0i + col;
    float yf = (float)y, xf = (float)x;
    // same arithmetic as reference (u,v are exact small ints)
    float u = __fsub_rn(yf, y0f), v = __fsub_rn(xf, x0f);
    float um = __fsub_rn(u, cc), vm = __fsub_rn(v, cc);
    float iu = __fsub_rn(__fadd_rn(cc, __fmul_rn(ca, um)), __fmul_rn(sa, vm));
    float iv = __fadd_rn(__fadd_rn(cc, __fmul_rn(sa, um)), __fmul_rn(ca, vm));
    float py = __fsub_rn(iu, top), px = __fsub_rn(iv, top);
    if (!(py >= 0.0f && py <= ph1 && px >= 0.0f && px <= ph1)) continue;

    // winner = max j with in_patch; skip if any j>k claims this pixel
    bool lose = false;
    for (int j = NBOX-1; j > k; --j){
      const float* bq = &sp[j*16];
      if (bq[12] == 0.0f) continue;
      float u2 = __fsub_rn(yf, bq[0]);
      if (!(u2 >= 0.0f && u2 < bq[2])) continue;
      float v2 = __fsub_rn(xf, bq[1]);
      if (!(v2 >= 0.0f && v2 < bq[2])) continue;
      float um2 = __fsub_rn(u2, bq[5]), vm2 = __fsub_rn(v2, bq[5]);
      float iu2 = __fsub_rn(__fadd_rn(bq[5], __fmul_rn(bq[6], um2)), __fmul_rn(bq[7], vm2));
      float iv2 = __fadd_rn(__fadd_rn(bq[5], __fmul_rn(bq[7], um2)), __fmul_rn(bq[6], vm2));
      float py2 = __fsub_rn(iu2, bq[4]), px2 = __fsub_rn(iv2, bq[4]);
      if (py2 >= 0.0f && py2 <= bq[13] && px2 >= 0.0f && px2 <= bq[13]){ lose = true; break; }
    }
    if (lose) continue;

    float sy = __fsub_rn(__fmul_rn(__fadd_rn(py, 0.5f), sres), 0.5f);
    float sx = __fsub_rn(__fmul_rn(__fadd_rn(px, 0.5f), sres), 0.5f);
    float fy = floorf(sy), fx = floorf(sx);
    float wy = __fsub_rn(sy, fy), wx = __fsub_rn(sx, fx);
    int y0t = (int)fminf(fmaxf(fy, 0.0f), 639.0f);
    int y1t = (int)fminf(fmaxf(__fadd_rn(fy, 1.0f), 0.0f), 639.0f);
    int x0t = (int)fminf(fmaxf(fx, 0.0f), 639.0f);
    int x1t = (int)fminf(fmaxf(__fadd_rn(fx, 1.0f), 0.0f), 639.0f);
    float w00 = (1.0f-wy)*(1.0f-wx), w01 = (1.0f-wy)*wx;
    float w10 = wy*(1.0f-wx),        w11 = wy*wx;
    int i00 = (y0t*PSZ + x0t)*3, i01 = (y0t*PSZ + x1t)*3;
    int i10 = (y1t*PSZ + x0t)*3, i11 = (y1t*PSZ + x1t)*3;
    int pix = y*IMW + x;
    size_t base = (size_t)b*IMG_ELEMS + (size_t)pix*3;
    #pragma unroll
    for (int c = 0; c < 3; c++){
      float wm = wbb[c], bd = wbb[3+c];
      float v00 = fminf(fmaxf(__fadd_rn(__fmul_rn(wm, patch[i00+c]), bd), -1.0f), 1.0f);
      v00 = fminf(fmaxf(__fadd_rn(v00, shf), -1.0f), 1.0f);
      float v01 = fminf(fmaxf(__fadd_rn(__fmul_rn(wm, patch[i01+c]), bd), -1.0f), 1.0f);
      v01 = fminf(fmaxf(__fadd_rn(v01, shf), -1.0f), 1.0f);
      float v10 = fminf(fmaxf(__fadd_rn(__fmul_rn(wm, patch[i10+c]), bd), -1.0f), 1.0f);
      v10 = fminf(fmaxf(__fadd_rn(v10, shf), -1.0f), 1.0f);
      float v11 = fminf(fmaxf(__fadd_rn(__fmul_rn(wm, patch[i11+c]), bd), -1.0f), 1.0f);
      v11 = fminf(fmaxf(__fadd_rn(v11, shf), -1.0f), 1.0f);
      float val = v00*w00 + v01*w01 + v10*w10 + v11*w11;
      float un = u01(rbits(n0, n1, (uint32_t)(pix*3 + c)));
      float span = __fsub_rn(0.01f, -0.01f);
      float nz = fmaxf(-0.01f, __fadd_rn(__fmul_rn(un, span), -0.01f));
      val = __fadd_rn(__fadd_rn(val, nz), delta);
      out[base + c] = fminf(fmaxf(val, -1.0f), 1.0f);
    }
  }
}

// ---------------- host launch ----------------
extern "C" void kernel_launch(void* const* d_in, const int* in_sizes, int n_in,
                              void* d_out, int out_size, void* d_ws, size_t ws_size,
                              hipStream_t stream){
  (void)in_sizes; (void)n_in; (void)out_size; (void)ws_size;
  const float* images = (const float*)d_in[0];
  const float* boxes  = (const float*)d_in[1];
  const float* patch  = (const float*)d_in[2];
  const float* scale  = (const float*)d_in[3];
  float* out = (float*)d_out;

  char* ws = (char*)d_ws;
  double* imgpart = (double*)(ws);              // 16*64*8  = 8192 B
  double* patpart = (double*)(ws + 8192);       // 8192 B
  float*  wb      = (float*)(ws + 16384);       // 512 B
  float*  shift   = (float*)(ws + 16896);       // 64 B
  float*  boxp    = (float*)(ws + 17408);       // 16384 B

  hipLaunchKernelGGL(k_seed,       dim3(1),                  dim3(64),  0, stream, wb);
  hipLaunchKernelGGL(k_copysum,    dim3(NIMG*RBLK),          dim3(256), 0, stream, images, out, imgpart);
  hipLaunchKernelGGL(k_patchsum16, dim3(64),                 dim3(256), 0, stream, patch, wb, patpart);
  hipLaunchKernelGGL(k_final,      dim3(1),                  dim3(256), 0, stream, imgpart, patpart, shift, boxp, boxes, scale);
  hipLaunchKernelGGL(k_render2,    dim3(NIMG*NBOX*RBOX_BLKS), dim3(256), 0, stream, patch, wb, shift, boxp, out);
}

// Round 4
// 139.304 us; speedup vs baseline: 1.1320x; 1.1043x over previous
//
#include <hip/hip_runtime.h>
#include <stdint.h>

// Problem constants (from setup_inputs: B=16,H=768,W=768,N=16,P=640)
#define NIMG 16
#define IMH 768
#define IMW 768
#define NBOX 16
#define PSZ 640
#define IMG_ELEMS (IMH*IMW*3)      // 1769472
#define PATCH_ELEMS (PSZ*PSZ*3)    // 1228800
#define CPBLK 128                  // copy-sum blocks per image
#define PATBLK 64                  // patch-sum blocks
#define RENDER_BLKS 4096

typedef float f4 __attribute__((ext_vector_type(4)));

// ---------------- threefry2x32 (JAX key schedule, 20 rounds) ----------------
__device__ __forceinline__ uint32_t rotl32(uint32_t v, int r){ return (v<<r)|(v>>(32-r)); }

__device__ __forceinline__ void threefry(uint32_t k0, uint32_t k1, uint32_t c0, uint32_t c1,
                                         uint32_t& o0, uint32_t& o1){
  uint32_t ks2 = k0 ^ k1 ^ 0x1BD11BDAu;
  uint32_t x0 = c0 + k0, x1 = c1 + k1;
#define TFR(r) { x0 += x1; x1 = rotl32(x1,(r)); x1 ^= x0; }
  TFR(13) TFR(15) TFR(26) TFR(6)
  x0 += k1;  x1 += ks2 + 1u;
  TFR(17) TFR(29) TFR(16) TFR(24)
  x0 += ks2; x1 += k0 + 2u;
  TFR(13) TFR(15) TFR(26) TFR(6)
  x0 += k0;  x1 += k1 + 3u;
  TFR(17) TFR(29) TFR(16) TFR(24)
  x0 += k1;  x1 += ks2 + 4u;
  TFR(13) TFR(15) TFR(26) TFR(6)
  x0 += ks2; x1 += k0 + 5u;
#undef TFR
  o0 = x0; o1 = x1;
}

__device__ __forceinline__ uint32_t rbits(uint32_t k0, uint32_t k1, uint32_t idx){
  uint32_t a, b; threefry(k0, k1, 0u, idx, a, b); return a ^ b;
}

__device__ __forceinline__ float u01(uint32_t bits){
  return __uint_as_float((bits >> 9) | 0x3f800000u) - 1.0f;
}

__device__ __forceinline__ float juniform(uint32_t k0, uint32_t k1, uint32_t idx, float mn, float mx){
  float u = u01(rbits(k0, k1, idx));
  float span = __fsub_rn(mx, mn);
  return fmaxf(mn, __fadd_rn(__fmul_rn(u, span), mn));
}

// XLA ErfInv f32 polynomial (value-path only; feeds wmul/badd)
__device__ float erfinv32(float x){
  float w = -log1pf(-x*x);
  float p;
  if (w < 5.0f){
    w = w - 2.5f;
    p = 2.81022636e-08f;
    p = fmaf(p,w, 3.43273939e-07f);
    p = fmaf(p,w,-3.5233877e-06f);
    p = fmaf(p,w,-4.39150654e-06f);
    p = fmaf(p,w, 0.00021858087f);
    p = fmaf(p,w,-0.00125372503f);
    p = fmaf(p,w,-0.00417768164f);
    p = fmaf(p,w, 0.246640727f);
    p = fmaf(p,w, 1.50140941f);
  } else {
    w = sqrtf(w) - 3.0f;
    p = -0.000200214257f;
    p = fmaf(p,w, 0.000100950558f);
    p = fmaf(p,w, 0.00134934322f);
    p = fmaf(p,w,-0.00367342844f);
    p = fmaf(p,w, 0.00573950773f);
    p = fmaf(p,w,-0.0076224613f);
    p = fmaf(p,w, 0.00943887047f);
    p = fmaf(p,w, 1.00167406f);
    p = fmaf(p,w, 2.83297682f);
  }
  return p * x;
}

// per-image wmul[3]/badd[3] into an 8-float record
__device__ __forceinline__ void compute_wb(int b, float* rec){
  uint32_t i0,i1; threefry(0u, 42u, 0u, (uint32_t)b, i0, i1);   // ikeys[b]
  uint32_t kw0,kw1; threefry(i0, i1, 0u, 0u, kw0, kw1);          // kw
  uint32_t kb0,kb1; threefry(i0, i1, 0u, 1u, kb0, kb1);          // kb
  const float lo = -0.99999994f;               // nextafter(-1,0)
  const float span = __fsub_rn(1.0f, lo);
  const float sq2 = 1.4142135623730951f;
  for (int j = 0; j < 3; j++){
    float uw = u01(rbits(kw0, kw1, (uint32_t)j));
    float rw = fmaxf(lo, __fadd_rn(__fmul_rn(uw, span), lo));
    float nw = __fmul_rn(sq2, erfinv32(rw));
    rec[j] = __fadd_rn(0.5f, __fmul_rn(0.1f, nw));               // wmul
    float ub = u01(rbits(kb0, kb1, (uint32_t)j));
    float rb = fmaxf(lo, __fadd_rn(__fmul_rn(ub, span), lo));
    float nb = __fmul_rn(sq2, erfinv32(rb));
    rec[3+j] = __fmul_rn(0.01f, nb);                             // badd
  }
  rec[6] = 0.0f; rec[7] = 0.0f;
}

// ---------------- K1: fused copy+imgsum (blocks 64..) & patchsum16 (0..63) --
__global__ __launch_bounds__(256) void k_front(const float* __restrict__ img,
                                               const float* __restrict__ patch,
                                               float* __restrict__ out,
                                               double* __restrict__ imgpart,
                                               double* __restrict__ patpart){
  if (blockIdx.x < PATBLK){
    // ---- patch path: seed wb in-block, 16 adjusted sums ----
    __shared__ float wl[NIMG*8];
    if (threadIdx.x < NIMG) compute_wb(threadIdx.x, &wl[threadIdx.x*8]);
    __syncthreads();
    double s[NIMG];
    #pragma unroll
    for (int im = 0; im < NIMG; im++) s[im] = 0.0;
    const f4* p4 = (const f4*)patch;
    const int N4 = PATCH_ELEMS/4;     // 307200
    for (int i = blockIdx.x*256 + threadIdx.x; i < N4; i += PATBLK*256){
      f4 v = __builtin_nontemporal_load(p4 + i);
      int c = (i << 2) % 3;
      #pragma unroll
      for (int q = 0; q < 4; q++){
        float pv = v[q];
        #pragma unroll
        for (int im = 0; im < NIMG; im++){
          float t = __fadd_rn(__fmul_rn(wl[im*8 + c], pv), wl[im*8 + 3 + c]);
          t = fminf(fmaxf(t, -1.0f), 1.0f);
          s[im] += (double)t;
        }
        c = (c == 2) ? 0 : c + 1;
      }
    }
    #pragma unroll
    for (int im = 0; im < NIMG; im++)
      for (int o = 32; o > 0; o >>= 1) s[im] += __shfl_down(s[im], o);
    __shared__ double red[4][NIMG];
    if ((threadIdx.x & 63) == 0){
      int w = threadIdx.x >> 6;
      #pragma unroll
      for (int im = 0; im < NIMG; im++) red[w][im] = s[im];
    }
    __syncthreads();
    if (threadIdx.x < NIMG){
      double t = red[0][threadIdx.x] + red[1][threadIdx.x] + red[2][threadIdx.x] + red[3][threadIdx.x];
      patpart[threadIdx.x*PATBLK + blockIdx.x] = t;
    }
  } else {
    // ---- copy + image-sum path ----
    int bi = blockIdx.x - PATBLK;
    int b = bi >> 7;                  // / CPBLK
    int j = bi & (CPBLK-1);
    const f4* src = (const f4*)(img + (size_t)b * IMG_ELEMS);
    f4* dst = (f4*)(out + (size_t)b * IMG_ELEMS);
    const int N4 = IMG_ELEMS/4;       // 442368
    double s = 0.0;
    for (int i = j*256 + threadIdx.x; i < N4; i += CPBLK*256){
      f4 v = __builtin_nontemporal_load(src + i);
      __builtin_nontemporal_store(v, dst + i);
      s += (double)v.x; s += (double)v.y; s += (double)v.z; s += (double)v.w;
    }
    for (int o = 32; o > 0; o >>= 1) s += __shfl_down(s, o);
    __shared__ double sm[4];
    if ((threadIdx.x & 63) == 0) sm[threadIdx.x >> 6] = s;
    __syncthreads();
    if (threadIdx.x == 0) imgpart[b*CPBLK + j] = sm[0]+sm[1]+sm[2]+sm[3];
  }
}

// ---------------- K2: finalize means/shift/wb + box params + chunk prefix ---
// box param layout (16 floats): 0:y0 1:x0 2:d 3:ph 4:top 5:c 6:ca 7:sa
//                               8:sres 9:delta 10:noisek0 11:noisek1 12:valid 13:ph-1
__global__ __launch_bounds__(256) void k_final(const double* __restrict__ imgpart,
                        const double* __restrict__ patpart,
                        float* __restrict__ shift, float* __restrict__ wbg,
                        float* __restrict__ boxp, int* __restrict__ chunkoff,
                        const float* __restrict__ boxes, const float* __restrict__ scale){
  int t = threadIdx.x;
  if (t < NIMG){
    double si = 0.0, sp = 0.0;
    for (int j = 0; j < CPBLK; j++) si += imgpart[t*CPBLK + j];
    for (int j = 0; j < PATBLK; j++) sp += patpart[t*PATBLK + j];
    float mi = (float)(si / (double)IMG_ELEMS);
    float mp = (float)(sp / (double)PATCH_ELEMS);
    shift[t] = __fsub_rn(mi, mp);
    compute_wb(t, &wbg[t*8]);
  }

  int nch = 0;
  {
    int b = t / NBOX, i = t % NBOX;
    uint32_t i0,i1;  threefry(0u, 42u, 0u, (uint32_t)b, i0, i1);     // ikeys[b]
    uint32_t kx0,kx1; threefry(i0, i1, 0u, 2u, kx0, kx1);            // kboxes
    uint32_t bk0,bk1; threefry(kx0, kx1, 0u, (uint32_t)i, bk0, bk1); // bkeys[i]
    uint32_t K1a,K1b,K2a,K2b,K3a,K3b,K4a,K4b,K5a,K5b;
    threefry(bk0,bk1,0u,0u,K1a,K1b);  // k1: oy jitter
    threefry(bk0,bk1,0u,1u,K2a,K2b);  // k2: ox jitter
    threefry(bk0,bk1,0u,2u,K3a,K3b);  // k3: angle
    threefry(bk0,bk1,0u,3u,K4a,K4b);  // k4: noise field
    threefry(bk0,bk1,0u,4u,K5a,K5b);  // k5: delta

    const float* bx = boxes + (size_t)t*4;
    float ymin = bx[0], xmin = bx[1], ymax = bx[2], xmax = bx[3];
    float bh = __fsub_rn(ymax, ymin);
    float bw = __fsub_rn(xmax, xmin);
    float longer = fmaxf(bh, bw);
    float sc = scale[0];
    float psize = floorf(__fmul_rn(longer, sc));
    float diag = fminf(__fmul_rn(1.4142135623730951f, psize), 768.0f);

    float mny = __fdiv_rn(__fmul_rn(-0.2f, bh), 2.0f);
    float mxy = __fdiv_rn(__fmul_rn( 0.2f, bh), 2.0f);
    float r1 = juniform(K1a, K1b, 0u, mny, mxy);
    float oy = __fadd_rn(__fadd_rn(ymin, __fdiv_rn(bh, 2.0f)), r1);
    float mnx = __fdiv_rn(__fmul_rn(-0.2f, bw), 2.0f);
    float mxx = __fdiv_rn(__fmul_rn( 0.2f, bw), 2.0f);
    float r2 = juniform(K2a, K2b, 0u, mnx, mxx);
    float ox = __fadd_rn(__fadd_rn(xmin, __fdiv_rn(bw, 2.0f)), r2);

    float hd = __fdiv_rn(diag, 2.0f);
    float y0 = fmaxf(__fsub_rn(oy, hd), 0.0f);
    float x0 = fmaxf(__fsub_rn(ox, hd), 0.0f);
    if (__fadd_rn(y0, diag) > 768.0f) y0 = __fsub_rn(768.0f, diag);
    if (__fadd_rn(x0, diag) > 768.0f) x0 = __fsub_rn(768.0f, diag);
    y0 = floorf(y0);
    x0 = floorf(x0);
    float d  = floorf(diag);
    float ph = psize;
    float top = floorf(__fdiv_rn(__fsub_rn(d, ph), 2.0f));

    const float A20 = 0.3490658503988659f;   // 20 deg in rad, f32
    float ang = juniform(K3a, K3b, 0u, -A20, A20);
    double da = (double)ang;
    float ca = (float)cos(da);
    float sa = (float)sin(da);
    float delta = juniform(K5a, K5b, 0u, -0.3f, 0.3f);
    float valid = (__fmul_rn(ph, ph) > 4.0f) ? 1.0f : 0.0f;
    float cc  = __fdiv_rn(__fsub_rn(d, 1.0f), 2.0f);
    float sres = __fdiv_rn(640.0f, ph);      // P / ph

    float* o = boxp + t*16;
    o[0]=y0; o[1]=x0; o[2]=d; o[3]=ph; o[4]=top; o[5]=cc; o[6]=ca; o[7]=sa;
    o[8]=sres; o[9]=delta;
    o[10]=__uint_as_float(K4a); o[11]=__uint_as_float(K4b);
    o[12]=valid; o[13]=__fsub_rn(ph, 1.0f); o[14]=0.0f; o[15]=0.0f;

    if (valid != 0.0f){
      int di = (int)d;
      nch = (di*di + 255) >> 8;
    }
  }

  // block-wide inclusive scan of nch over 256 threads
  __shared__ int scan[256];
  scan[t] = nch; __syncthreads();
  for (int off = 1; off < 256; off <<= 1){
    int v = (t >= off) ? scan[t-off] : 0;
    __syncthreads();
    scan[t] += v;
    __syncthreads();
  }
  if (t == 0) chunkoff[0] = 0;
  chunkoff[t+1] = scan[t];
}

// ---------------- K3: dense chunked render ----------------------------------
__global__ __launch_bounds__(256) void k_render3(
    const float* __restrict__ patch, const float* __restrict__ wbg,
    const float* __restrict__ shiftg, const float* __restrict__ boxp,
    const int* __restrict__ chunkoff, float* __restrict__ out)
{
  __shared__ float sp[256*16];     // all 256 (image,box) param records
  __shared__ float wl[NIMG*8];
  __shared__ float shl[NIMG];
  __shared__ int   coff[258];
  for (int i = threadIdx.x; i < 4096; i += 256) sp[i] = boxp[i];
  if (threadIdx.x < NIMG*8) wl[threadIdx.x] = wbg[threadIdx.x];
  if (threadIdx.x < NIMG)   shl[threadIdx.x] = shiftg[threadIdx.x];
  for (int i = threadIdx.x; i < 257; i += 256) coff[i] = chunkoff[i];  // FIX: covers coff[256]
  __syncthreads();
  int total = coff[256];

  for (int chunk = blockIdx.x; chunk < total; chunk += RENDER_BLKS){
    // binary search: s = max{ s in [0,256) : coff[s] <= chunk }
    int lo = 0, hi = 255;
    #pragma unroll
    for (int it = 0; it < 8; it++){
      int mid = (lo + hi + 1) >> 1;
      if (coff[mid] <= chunk) lo = mid; else hi = mid - 1;
    }
    int s = lo;
    const float* bp = &sp[s*16];
    int d = (int)bp[2];
    int dd = d*d;
    int idx = (chunk - coff[s])*256 + (int)threadIdx.x;
    if (idx >= dd) continue;

    int b = s >> 4, k = s & 15;
    float y0f = bp[0], x0f = bp[1];
    float cc = bp[5], ca = bp[6], sa = bp[7], top = bp[4];
    float ph1 = bp[13], sres = bp[8], delta = bp[9];

    int row = idx / d;
    int col = idx - row*d;
    int y = (int)y0f + row, x = (int)x0f + col;
    float yf = (float)y, xf = (float)x;
    float u = __fsub_rn(yf, y0f), v = __fsub_rn(xf, x0f);
    float um = __fsub_rn(u, cc), vm = __fsub_rn(v, cc);
    float iu = __fsub_rn(__fadd_rn(cc, __fmul_rn(ca, um)), __fmul_rn(sa, vm));
    float iv = __fadd_rn(__fadd_rn(cc, __fmul_rn(sa, um)), __fmul_rn(ca, vm));
    float py = __fsub_rn(iu, top), px = __fsub_rn(iv, top);
    if (!(py >= 0.0f && py <= ph1 && px >= 0.0f && px <= ph1)) continue;

    // winner = max j with in_patch; skip if any j>k claims this pixel
    bool lose = false;
    for (int j = NBOX-1; j > k; --j){
      const float* bq = &sp[(b*NBOX + j)*16];
      if (bq[12] == 0.0f) continue;
      float u2 = __fsub_rn(yf, bq[0]);
      if (!(u2 >= 0.0f && u2 < bq[2])) continue;
      float v2 = __fsub_rn(xf, bq[1]);
      if (!(v2 >= 0.0f && v2 < bq[2])) continue;
      float um2 = __fsub_rn(u2, bq[5]), vm2 = __fsub_rn(v2, bq[5]);
      float iu2 = __fsub_rn(__fadd_rn(bq[5], __fmul_rn(bq[6], um2)), __fmul_rn(bq[7], vm2));
      float iv2 = __fadd_rn(__fadd_rn(bq[5], __fmul_rn(bq[7], um2)), __fmul_rn(bq[6], vm2));
      float py2 = __fsub_rn(iu2, bq[4]), px2 = __fsub_rn(iv2, bq[4]);
      if (py2 >= 0.0f && py2 <= bq[13] && px2 >= 0.0f && px2 <= bq[13]){ lose = true; break; }
    }
    if (lose) continue;

    float sy = __fsub_rn(__fmul_rn(__fadd_rn(py, 0.5f), sres), 0.5f);
    float sx = __fsub_rn(__fmul_rn(__fadd_rn(px, 0.5f), sres), 0.5f);
    float fy = floorf(sy), fx = floorf(sx);
    float wy = __fsub_rn(sy, fy), wx = __fsub_rn(sx, fx);
    int y0t = (int)fminf(fmaxf(fy, 0.0f), 639.0f);
    int y1t = (int)fminf(fmaxf(__fadd_rn(fy, 1.0f), 0.0f), 639.0f);
    int x0t = (int)fminf(fmaxf(fx, 0.0f), 639.0f);
    int x1t = (int)fminf(fmaxf(__fadd_rn(fx, 1.0f), 0.0f), 639.0f);
    float w00 = (1.0f-wy)*(1.0f-wx), w01 = (1.0f-wy)*wx;
    float w10 = wy*(1.0f-wx),        w11 = wy*wx;
    int i00 = (y0t*PSZ + x0t)*3, i01 = (y0t*PSZ + x1t)*3;
    int i10 = (y1t*PSZ + x0t)*3, i11 = (y1t*PSZ + x1t)*3;
    const float* wbb = &wl[b*8];
    float shf = shl[b];
    uint32_t n0 = __float_as_uint(bp[10]);
    uint32_t n1 = __float_as_uint(bp[11]);
    int pix = y*IMW + x;
    size_t base = (size_t)b*IMG_ELEMS + (size_t)pix*3;
    #pragma unroll
    for (int c = 0; c < 3; c++){
      float wm = wbb[c], bd = wbb[3+c];
      float v00 = fminf(fmaxf(__fadd_rn(__fmul_rn(wm, patch[i00+c]), bd), -1.0f), 1.0f);
      v00 = fminf(fmaxf(__fadd_rn(v00, shf), -1.0f), 1.0f);
      float v01 = fminf(fmaxf(__fadd_rn(__fmul_rn(wm, patch[i01+c]), bd), -1.0f), 1.0f);
      v01 = fminf(fmaxf(__fadd_rn(v01, shf), -1.0f), 1.0f);
      float v10 = fminf(fmaxf(__fadd_rn(__fmul_rn(wm, patch[i10+c]), bd), -1.0f), 1.0f);
      v10 = fminf(fmaxf(__fadd_rn(v10, shf), -1.0f), 1.0f);
      float v11 = fminf(fmaxf(__fadd_rn(__fmul_rn(wm, patch[i11+c]), bd), -1.0f), 1.0f);
      v11 = fminf(fmaxf(__fadd_rn(v11, shf), -1.0f), 1.0f);
      float val = v00*w00 + v01*w01 + v10*w10 + v11*w11;
      float un = u01(rbits(n0, n1, (uint32_t)(pix*3 + c)));
      float span = __fsub_rn(0.01f, -0.01f);
      float nz = fmaxf(-0.01f, __fadd_rn(__fmul_rn(un, span), -0.01f));
      val = __fadd_rn(__fadd_rn(val, nz), delta);
      out[base + c] = fminf(fmaxf(val, -1.0f), 1.0f);
    }
  }
}

// ---------------- host launch ----------------
extern "C" void kernel_launch(void* const* d_in, const int* in_sizes, int n_in,
                              void* d_out, int out_size, void* d_ws, size_t ws_size,
                              hipStream_t stream){
  (void)in_sizes; (void)n_in; (void)out_size; (void)ws_size;
  const float* images = (const float*)d_in[0];
  const float* boxes  = (const float*)d_in[1];
  const float* patch  = (const float*)d_in[2];
  const float* scale  = (const float*)d_in[3];
  float* out = (float*)d_out;

  char* ws = (char*)d_ws;
  double* imgpart = (double*)(ws);               // 16*128*8 = 16384 B
  double* patpart = (double*)(ws + 16384);       // 16*64*8  = 8192 B
  float*  wb      = (float*)(ws + 24576);        // 512 B
  float*  shift   = (float*)(ws + 25088);        // 64 B (pad to 25600)
  float*  boxp    = (float*)(ws + 25600);        // 16384 B
  int*    chunkoff= (int*)(ws + 41984);          // 258*4 = 1032 B (total ~43 KB)

  hipLaunchKernelGGL(k_front,   dim3(PATBLK + NIMG*CPBLK), dim3(256), 0, stream,
                     images, patch, out, imgpart, patpart);
  hipLaunchKernelGGL(k_final,   dim3(1), dim3(256), 0, stream,
                     imgpart, patpart, shift, wb, boxp, chunkoff, boxes, scale);
  hipLaunchKernelGGL(k_render3, dim3(RENDER_BLKS), dim3(256), 0, stream,
                     patch, wb, shift, boxp, chunkoff, out);
}

// Round 5
// 139.074 us; speedup vs baseline: 1.1338x; 1.0017x over previous
//
#include <hip/hip_runtime.h>
#include <stdint.h>

// Problem constants (from setup_inputs: B=16,H=768,W=768,N=16,P=640)
#define NIMG 16
#define IMH 768
#define IMW 768
#define NBOX 16
#define PSZ 640
#define IMG_ELEMS (IMH*IMW*3)      // 1769472
#define PATCH_ELEMS (PSZ*PSZ*3)    // 1228800
#define CPBLK 128                  // copy-sum blocks per image
#define PATBLK 64                  // patch-sum blocks
#define PADBLK 64                  // patch-padding blocks
#define RENDER_BLKS 4096

typedef float f4 __attribute__((ext_vector_type(4)));

// ---------------- threefry2x32 (JAX key schedule, 20 rounds) ----------------
__device__ __forceinline__ uint32_t rotl32(uint32_t v, int r){ return (v<<r)|(v>>(32-r)); }

__device__ __forceinline__ void threefry(uint32_t k0, uint32_t k1, uint32_t c0, uint32_t c1,
                                         uint32_t& o0, uint32_t& o1){
  uint32_t ks2 = k0 ^ k1 ^ 0x1BD11BDAu;
  uint32_t x0 = c0 + k0, x1 = c1 + k1;
#define TFR(r) { x0 += x1; x1 = rotl32(x1,(r)); x1 ^= x0; }
  TFR(13) TFR(15) TFR(26) TFR(6)
  x0 += k1;  x1 += ks2 + 1u;
  TFR(17) TFR(29) TFR(16) TFR(24)
  x0 += ks2; x1 += k0 + 2u;
  TFR(13) TFR(15) TFR(26) TFR(6)
  x0 += k0;  x1 += k1 + 3u;
  TFR(17) TFR(29) TFR(16) TFR(24)
  x0 += k1;  x1 += ks2 + 4u;
  TFR(13) TFR(15) TFR(26) TFR(6)
  x0 += ks2; x1 += k0 + 5u;
#undef TFR
  o0 = x0; o1 = x1;
}

__device__ __forceinline__ uint32_t rbits(uint32_t k0, uint32_t k1, uint32_t idx){
  uint32_t a, b; threefry(k0, k1, 0u, idx, a, b); return a ^ b;
}

__device__ __forceinline__ float u01(uint32_t bits){
  return __uint_as_float((bits >> 9) | 0x3f800000u) - 1.0f;
}

__device__ __forceinline__ float juniform(uint32_t k0, uint32_t k1, uint32_t idx, float mn, float mx){
  float u = u01(rbits(k0, k1, idx));
  float span = __fsub_rn(mx, mn);
  return fmaxf(mn, __fadd_rn(__fmul_rn(u, span), mn));
}

// XLA ErfInv f32 polynomial (value-path only; feeds wmul/badd)
__device__ float erfinv32(float x){
  float w = -log1pf(-x*x);
  float p;
  if (w < 5.0f){
    w = w - 2.5f;
    p = 2.81022636e-08f;
    p = fmaf(p,w, 3.43273939e-07f);
    p = fmaf(p,w,-3.5233877e-06f);
    p = fmaf(p,w,-4.39150654e-06f);
    p = fmaf(p,w, 0.00021858087f);
    p = fmaf(p,w,-0.00125372503f);
    p = fmaf(p,w,-0.00417768164f);
    p = fmaf(p,w, 0.246640727f);
    p = fmaf(p,w, 1.50140941f);
  } else {
    w = sqrtf(w) - 3.0f;
    p = -0.000200214257f;
    p = fmaf(p,w, 0.000100950558f);
    p = fmaf(p,w, 0.00134934322f);
    p = fmaf(p,w,-0.00367342844f);
    p = fmaf(p,w, 0.00573950773f);
    p = fmaf(p,w,-0.0076224613f);
    p = fmaf(p,w, 0.00943887047f);
    p = fmaf(p,w, 1.00167406f);
    p = fmaf(p,w, 2.83297682f);
  }
  return p * x;
}

// per-image wmul[3]/badd[3] into an 8-float record
__device__ __forceinline__ void compute_wb(int b, float* rec){
  uint32_t i0,i1; threefry(0u, 42u, 0u, (uint32_t)b, i0, i1);   // ikeys[b]
  uint32_t kw0,kw1; threefry(i0, i1, 0u, 0u, kw0, kw1);          // kw
  uint32_t kb0,kb1; threefry(i0, i1, 0u, 1u, kb0, kb1);          // kb
  const float lo = -0.99999994f;               // nextafter(-1,0)
  const float span = __fsub_rn(1.0f, lo);
  const float sq2 = 1.4142135623730951f;
  for (int j = 0; j < 3; j++){
    float uw = u01(rbits(kw0, kw1, (uint32_t)j));
    float rw = fmaxf(lo, __fadd_rn(__fmul_rn(uw, span), lo));
    float nw = __fmul_rn(sq2, erfinv32(rw));
    rec[j] = __fadd_rn(0.5f, __fmul_rn(0.1f, nw));               // wmul
    float ub = u01(rbits(kb0, kb1, (uint32_t)j));
    float rb = fmaxf(lo, __fadd_rn(__fmul_rn(ub, span), lo));
    float nb = __fmul_rn(sq2, erfinv32(rb));
    rec[3+j] = __fmul_rn(0.01f, nb);                             // badd
  }
  rec[6] = 0.0f; rec[7] = 0.0f;
}

// ---------------- K1: fused patchsum16 | copy+imgsum | patch-pad ------------
__global__ __launch_bounds__(256) void k_front(const float* __restrict__ img,
                                               const float* __restrict__ patch,
                                               float* __restrict__ out,
                                               double* __restrict__ imgpart,
                                               double* __restrict__ patpart,
                                               f4* __restrict__ pad4, int do_pad){
  if (blockIdx.x < PATBLK){
    // ---- patch path: seed wb in-block, 16 adjusted sums ----
    __shared__ float wl[NIMG*8];
    if (threadIdx.x < NIMG) compute_wb(threadIdx.x, &wl[threadIdx.x*8]);
    __syncthreads();
    double s[NIMG];
    #pragma unroll
    for (int im = 0; im < NIMG; im++) s[im] = 0.0;
    const f4* p4 = (const f4*)patch;
    const int N4 = PATCH_ELEMS/4;     // 307200
    for (int i = blockIdx.x*256 + threadIdx.x; i < N4; i += PATBLK*256){
      f4 v = p4[i];
      int c = (i << 2) % 3;
      #pragma unroll
      for (int q = 0; q < 4; q++){
        float pv = v[q];
        #pragma unroll
        for (int im = 0; im < NIMG; im++){
          float t = __fadd_rn(__fmul_rn(wl[im*8 + c], pv), wl[im*8 + 3 + c]);
          t = fminf(fmaxf(t, -1.0f), 1.0f);
          s[im] += (double)t;
        }
        c = (c == 2) ? 0 : c + 1;
      }
    }
    #pragma unroll
    for (int im = 0; im < NIMG; im++)
      for (int o = 32; o > 0; o >>= 1) s[im] += __shfl_down(s[im], o);
    __shared__ double red[4][NIMG];
    if ((threadIdx.x & 63) == 0){
      int w = threadIdx.x >> 6;
      #pragma unroll
      for (int im = 0; im < NIMG; im++) red[w][im] = s[im];
    }
    __syncthreads();
    if (threadIdx.x < NIMG){
      double t = red[0][threadIdx.x] + red[1][threadIdx.x] + red[2][threadIdx.x] + red[3][threadIdx.x];
      patpart[threadIdx.x*PATBLK + blockIdx.x] = t;
    }
  } else if (blockIdx.x < PATBLK + NIMG*CPBLK){
    // ---- copy + image-sum path (cached loads/stores, float accumulate) ----
    int bi = blockIdx.x - PATBLK;
    int b = bi >> 7;                  // / CPBLK
    int j = bi & (CPBLK-1);
    const f4* src = (const f4*)(img + (size_t)b * IMG_ELEMS);
    f4* dst = (f4*)(out + (size_t)b * IMG_ELEMS);
    const int N4 = IMG_ELEMS/4;       // 442368 ; /(128*256) = 13.5
    f4 fs = {0.0f, 0.0f, 0.0f, 0.0f};
    #pragma unroll 2
    for (int i = j*256 + threadIdx.x; i < N4; i += CPBLK*256){
      f4 v = src[i];
      dst[i] = v;
      fs += v;
    }
    double s = ((double)fs.x + (double)fs.y) + ((double)fs.z + (double)fs.w);
    for (int o = 32; o > 0; o >>= 1) s += __shfl_down(s, o);
    __shared__ double sm[4];
    if ((threadIdx.x & 63) == 0) sm[threadIdx.x >> 6] = s;
    __syncthreads();
    if (threadIdx.x == 0) imgpart[b*CPBLK + j] = sm[0]+sm[1]+sm[2]+sm[3];
  } else {
    // ---- patch padding path: {r,g,b} -> 16B texels in ws ----
    if (!do_pad) return;
    int pb = blockIdx.x - (PATBLK + NIMG*CPBLK);
    const f4* src = (const f4*)patch;
    const int NG = PSZ*PSZ/4;         // 102400 groups of 4 texels (=3 f4 reads)
    for (int g = pb*256 + threadIdx.x; g < NG; g += PADBLK*256){
      f4 a = src[g*3+0], b2 = src[g*3+1], c2 = src[g*3+2];
      f4 t0 = {a.x,  a.y,  a.z,  0.0f};
      f4 t1 = {a.w,  b2.x, b2.y, 0.0f};
      f4 t2 = {b2.z, b2.w, c2.x, 0.0f};
      f4 t3 = {c2.y, c2.z, c2.w, 0.0f};
      pad4[g*4+0] = t0; pad4[g*4+1] = t1; pad4[g*4+2] = t2; pad4[g*4+3] = t3;
    }
  }
}

// ---------------- K2: finalize means/shift/wb + box params + chunk prefix ---
// box param layout (16 floats): 0:y0 1:x0 2:d 3:ph 4:top 5:c 6:ca 7:sa
//                               8:sres 9:delta 10:noisek0 11:noisek1 12:valid 13:ph-1
__global__ __launch_bounds__(256) void k_final(const double* __restrict__ imgpart,
                        const double* __restrict__ patpart,
                        float* __restrict__ shift, float* __restrict__ wbg,
                        float* __restrict__ boxp, int* __restrict__ chunkoff,
                        const float* __restrict__ boxes, const float* __restrict__ scale){
  int t = threadIdx.x;
  // parallel partial reduction: 16 lanes per image
  {
    int im = t >> 4, l = t & 15;
    double si = 0.0, sp = 0.0;
    #pragma unroll
    for (int j = 0; j < CPBLK/16; j++) si += imgpart[im*CPBLK + l + j*16];
    #pragma unroll
    for (int j = 0; j < PATBLK/16; j++) sp += patpart[im*PATBLK + l + j*16];
    #pragma unroll
    for (int o = 8; o > 0; o >>= 1){ si += __shfl_down(si, o); sp += __shfl_down(sp, o); }
    if (l == 0){
      float mi = (float)(si / (double)IMG_ELEMS);
      float mp = (float)(sp / (double)PATCH_ELEMS);
      shift[im] = __fsub_rn(mi, mp);
      compute_wb(im, &wbg[im*8]);
    }
  }

  int nch = 0;
  {
    int b = t / NBOX, i = t % NBOX;
    uint32_t i0,i1;  threefry(0u, 42u, 0u, (uint32_t)b, i0, i1);     // ikeys[b]
    uint32_t kx0,kx1; threefry(i0, i1, 0u, 2u, kx0, kx1);            // kboxes
    uint32_t bk0,bk1; threefry(kx0, kx1, 0u, (uint32_t)i, bk0, bk1); // bkeys[i]
    uint32_t K1a,K1b,K2a,K2b,K3a,K3b,K4a,K4b,K5a,K5b;
    threefry(bk0,bk1,0u,0u,K1a,K1b);  // k1: oy jitter
    threefry(bk0,bk1,0u,1u,K2a,K2b);  // k2: ox jitter
    threefry(bk0,bk1,0u,2u,K3a,K3b);  // k3: angle
    threefry(bk0,bk1,0u,3u,K4a,K4b);  // k4: noise field
    threefry(bk0,bk1,0u,4u,K5a,K5b);  // k5: delta

    const float* bx = boxes + (size_t)t*4;
    float ymin = bx[0], xmin = bx[1], ymax = bx[2], xmax = bx[3];
    float bh = __fsub_rn(ymax, ymin);
    float bw = __fsub_rn(xmax, xmin);
    float longer = fmaxf(bh, bw);
    float sc = scale[0];
    float psize = floorf(__fmul_rn(longer, sc));
    float diag = fminf(__fmul_rn(1.4142135623730951f, psize), 768.0f);

    float mny = __fdiv_rn(__fmul_rn(-0.2f, bh), 2.0f);
    float mxy = __fdiv_rn(__fmul_rn( 0.2f, bh), 2.0f);
    float r1 = juniform(K1a, K1b, 0u, mny, mxy);
    float oy = __fadd_rn(__fadd_rn(ymin, __fdiv_rn(bh, 2.0f)), r1);
    float mnx = __fdiv_rn(__fmul_rn(-0.2f, bw), 2.0f);
    float mxx = __fdiv_rn(__fmul_rn( 0.2f, bw), 2.0f);
    float r2 = juniform(K2a, K2b, 0u, mnx, mxx);
    float ox = __fadd_rn(__fadd_rn(xmin, __fdiv_rn(bw, 2.0f)), r2);

    float hd = __fdiv_rn(diag, 2.0f);
    float y0 = fmaxf(__fsub_rn(oy, hd), 0.0f);
    float x0 = fmaxf(__fsub_rn(ox, hd), 0.0f);
    if (__fadd_rn(y0, diag) > 768.0f) y0 = __fsub_rn(768.0f, diag);
    if (__fadd_rn(x0, diag) > 768.0f) x0 = __fsub_rn(768.0f, diag);
    y0 = floorf(y0);
    x0 = floorf(x0);
    float d  = floorf(diag);
    float ph = psize;
    float top = floorf(__fdiv_rn(__fsub_rn(d, ph), 2.0f));

    const float A20 = 0.3490658503988659f;   // 20 deg in rad, f32
    float ang = juniform(K3a, K3b, 0u, -A20, A20);
    double da = (double)ang;
    float ca = (float)cos(da);
    float sa = (float)sin(da);
    float delta = juniform(K5a, K5b, 0u, -0.3f, 0.3f);
    float valid = (__fmul_rn(ph, ph) > 4.0f) ? 1.0f : 0.0f;
    float cc  = __fdiv_rn(__fsub_rn(d, 1.0f), 2.0f);
    float sres = __fdiv_rn(640.0f, ph);      // P / ph

    float* o = boxp + t*16;
    o[0]=y0; o[1]=x0; o[2]=d; o[3]=ph; o[4]=top; o[5]=cc; o[6]=ca; o[7]=sa;
    o[8]=sres; o[9]=delta;
    o[10]=__uint_as_float(K4a); o[11]=__uint_as_float(K4b);
    o[12]=valid; o[13]=__fsub_rn(ph, 1.0f); o[14]=0.0f; o[15]=0.0f;

    if (valid != 0.0f){
      int di = (int)d;
      nch = (di*di + 255) >> 8;
    }
  }

  // block-wide inclusive scan of nch over 256 threads
  __shared__ int scan[256];
  scan[t] = nch; __syncthreads();
  for (int off = 1; off < 256; off <<= 1){
    int v = (t >= off) ? scan[t-off] : 0;
    __syncthreads();
    scan[t] += v;
    __syncthreads();
  }
  if (t == 0) chunkoff[0] = 0;
  chunkoff[t+1] = scan[t];
}

// ---------------- K3: dense chunked render ----------------------------------
template<int USEPAD>
__global__ __launch_bounds__(256) void k_render3(
    const float* __restrict__ patch, const f4* __restrict__ pad4,
    const float* __restrict__ wbg, const float* __restrict__ shiftg,
    const float* __restrict__ boxp, const int* __restrict__ chunkoff,
    float* __restrict__ out)
{
  __shared__ float sp[256*16];     // all 256 (image,box) param records
  __shared__ float wl[NIMG*8];
  __shared__ float shl[NIMG];
  __shared__ int   coff[258];
  for (int i = threadIdx.x; i < 4096; i += 256) sp[i] = boxp[i];
  if (threadIdx.x < NIMG*8) wl[threadIdx.x] = wbg[threadIdx.x];
  if (threadIdx.x < NIMG)   shl[threadIdx.x] = shiftg[threadIdx.x];
  for (int i = threadIdx.x; i < 257; i += 256) coff[i] = chunkoff[i];
  __syncthreads();
  int total = coff[256];

  for (int chunk = blockIdx.x; chunk < total; chunk += RENDER_BLKS){
    // binary search: s = max{ s in [0,256) : coff[s] <= chunk }
    int lo = 0, hi = 255;
    #pragma unroll
    for (int it = 0; it < 8; it++){
      int mid = (lo + hi + 1) >> 1;
      if (coff[mid] <= chunk) lo = mid; else hi = mid - 1;
    }
    int s = lo;
    const float* bp = &sp[s*16];
    int d = (int)bp[2];
    int dd = d*d;
    int idx = (chunk - coff[s])*256 + (int)threadIdx.x;
    if (idx >= dd) continue;

    int b = s >> 4, k = s & 15;
    float y0f = bp[0], x0f = bp[1];
    float cc = bp[5], ca = bp[6], sa = bp[7], top = bp[4];
    float ph1 = bp[13], sres = bp[8], delta = bp[9];

    int row = idx / d;
    int col = idx - row*d;
    int y = (int)y0f + row, x = (int)x0f + col;
    float yf = (float)y, xf = (float)x;
    float u = __fsub_rn(yf, y0f), v = __fsub_rn(xf, x0f);
    float um = __fsub_rn(u, cc), vm = __fsub_rn(v, cc);
    float iu = __fsub_rn(__fadd_rn(cc, __fmul_rn(ca, um)), __fmul_rn(sa, vm));
    float iv = __fadd_rn(__fadd_rn(cc, __fmul_rn(sa, um)), __fmul_rn(ca, vm));
    float py = __fsub_rn(iu, top), px = __fsub_rn(iv, top);
    if (!(py >= 0.0f && py <= ph1 && px >= 0.0f && px <= ph1)) continue;

    // winner = max j with in_patch; skip if any j>k claims this pixel
    bool lose = false;
    for (int j = NBOX-1; j > k; --j){
      const float* bq = &sp[(b*NBOX + j)*16];
      if (bq[12] == 0.0f) continue;
      float u2 = __fsub_rn(yf, bq[0]);
      if (!(u2 >= 0.0f && u2 < bq[2])) continue;
      float v2 = __fsub_rn(xf, bq[1]);
      if (!(v2 >= 0.0f && v2 < bq[2])) continue;
      float um2 = __fsub_rn(u2, bq[5]), vm2 = __fsub_rn(v2, bq[5]);
      float iu2 = __fsub_rn(__fadd_rn(bq[5], __fmul_rn(bq[6], um2)), __fmul_rn(bq[7], vm2));
      float iv2 = __fadd_rn(__fadd_rn(bq[5], __fmul_rn(bq[7], um2)), __fmul_rn(bq[6], vm2));
      float py2 = __fsub_rn(iu2, bq[4]), px2 = __fsub_rn(iv2, bq[4]);
      if (py2 >= 0.0f && py2 <= bq[13] && px2 >= 0.0f && px2 <= bq[13]){ lose = true; break; }
    }
    if (lose) continue;

    float sy = __fsub_rn(__fmul_rn(__fadd_rn(py, 0.5f), sres), 0.5f);
    float sx = __fsub_rn(__fmul_rn(__fadd_rn(px, 0.5f), sres), 0.5f);
    float fy = floorf(sy), fx = floorf(sx);
    float wy = __fsub_rn(sy, fy), wx = __fsub_rn(sx, fx);
    int y0t = (int)fminf(fmaxf(fy, 0.0f), 639.0f);
    int y1t = (int)fminf(fmaxf(__fadd_rn(fy, 1.0f), 0.0f), 639.0f);
    int x0t = (int)fminf(fmaxf(fx, 0.0f), 639.0f);
    int x1t = (int)fminf(fmaxf(__fadd_rn(fx, 1.0f), 0.0f), 639.0f);
    float w00 = (1.0f-wy)*(1.0f-wx), w01 = (1.0f-wy)*wx;
    float w10 = wy*(1.0f-wx),        w11 = wy*wx;
    const float* wbb = &wl[b*8];
    float shf = shl[b];
    uint32_t n0 = __float_as_uint(bp[10]);
    uint32_t n1 = __float_as_uint(bp[11]);
    int pix = y*IMW + x;
    size_t base = (size_t)b*IMG_ELEMS + (size_t)pix*3;

    f4 p00, p01, p10, p11;
    int i00, i01, i10, i11;
    if constexpr (USEPAD){
      p00 = pad4[y0t*PSZ + x0t]; p01 = pad4[y0t*PSZ + x1t];
      p10 = pad4[y1t*PSZ + x0t]; p11 = pad4[y1t*PSZ + x1t];
      i00 = i01 = i10 = i11 = 0;
    } else {
      i00 = (y0t*PSZ + x0t)*3; i01 = (y0t*PSZ + x1t)*3;
      i10 = (y1t*PSZ + x0t)*3; i11 = (y1t*PSZ + x1t)*3;
    }
    #pragma unroll
    for (int c = 0; c < 3; c++){
      float wm = wbb[c], bd = wbb[3+c];
      float t00, t01, t10, t11;
      if constexpr (USEPAD){ t00 = p00[c]; t01 = p01[c]; t10 = p10[c]; t11 = p11[c]; }
      else { t00 = patch[i00+c]; t01 = patch[i01+c]; t10 = patch[i10+c]; t11 = patch[i11+c]; }
      float v00 = fminf(fmaxf(__fadd_rn(__fmul_rn(wm, t00), bd), -1.0f), 1.0f);
      v00 = fminf(fmaxf(__fadd_rn(v00, shf), -1.0f), 1.0f);
      float v01 = fminf(fmaxf(__fadd_rn(__fmul_rn(wm, t01), bd), -1.0f), 1.0f);
      v01 = fminf(fmaxf(__fadd_rn(v01, shf), -1.0f), 1.0f);
      float v10 = fminf(fmaxf(__fadd_rn(__fmul_rn(wm, t10), bd), -1.0f), 1.0f);
      v10 = fminf(fmaxf(__fadd_rn(v10, shf), -1.0f), 1.0f);
      float v11 = fminf(fmaxf(__fadd_rn(__fmul_rn(wm, t11), bd), -1.0f), 1.0f);
      v11 = fminf(fmaxf(__fadd_rn(v11, shf), -1.0f), 1.0f);
      float val = v00*w00 + v01*w01 + v10*w10 + v11*w11;
      float un = u01(rbits(n0, n1, (uint32_t)(pix*3 + c)));
      float span = __fsub_rn(0.01f, -0.01f);
      float nz = fmaxf(-0.01f, __fadd_rn(__fmul_rn(un, span), -0.01f));
      val = __fadd_rn(__fadd_rn(val, nz), delta);
      out[base + c] = fminf(fmaxf(val, -1.0f), 1.0f);
    }
  }
}

// ---------------- host launch ----------------
extern "C" void kernel_launch(void* const* d_in, const int* in_sizes, int n_in,
                              void* d_out, int out_size, void* d_ws, size_t ws_size,
                              hipStream_t stream){
  (void)in_sizes; (void)n_in; (void)out_size;
  const float* images = (const float*)d_in[0];
  const float* boxes  = (const float*)d_in[1];
  const float* patch  = (const float*)d_in[2];
  const float* scale  = (const float*)d_in[3];
  float* out = (float*)d_out;

  char* ws = (char*)d_ws;
  double* imgpart = (double*)(ws);               // 16*128*8 = 16384 B
  double* patpart = (double*)(ws + 16384);       // 16*64*8  = 8192 B
  float*  wb      = (float*)(ws + 24576);        // 512 B
  float*  shift   = (float*)(ws + 25088);        // 64 B
  float*  boxp    = (float*)(ws + 25600);        // 16384 B
  int*    chunkoff= (int*)(ws + 41984);          // 1032 B
  f4*     pad4    = (f4*)(ws + 65536);           // 640*640*16 = 6553600 B

  size_t need = 65536 + (size_t)PSZ*PSZ*16;
  int do_pad = (ws_size >= need) ? 1 : 0;

  int front_blks = PATBLK + NIMG*CPBLK + (do_pad ? PADBLK : 0);
  hipLaunchKernelGGL(k_front,   dim3(front_blks), dim3(256), 0, stream,
                     images, patch, out, imgpart, patpart, pad4, do_pad);
  hipLaunchKernelGGL(k_final,   dim3(1), dim3(256), 0, stream,
                     imgpart, patpart, shift, wb, boxp, chunkoff, boxes, scale);
  if (do_pad)
    hipLaunchKernelGGL(k_render3<1>, dim3(RENDER_BLKS), dim3(256), 0, stream,
                       patch, pad4, wb, shift, boxp, chunkoff, out);
  else
    hipLaunchKernelGGL(k_render3<0>, dim3(RENDER_BLKS), dim3(256), 0, stream,
                       patch, pad4, wb, shift, boxp, chunkoff, out);
}